// Round 6
// baseline (743.614 us; speedup 1.0000x reference)
//
#include <hip/hip_runtime.h>
#include <hip/hip_bf16.h>

// GCN layer: out = relu( (D^-1/2 A D^-1/2) (x @ w) + b )
//
// R11 = MEASUREMENT ROUND (kernels byte-identical to R10's 589.2 us).
//   Ledger: aggb 248 (measured) + gemm ~70 (R7 3x-probe) leaves ~271 us
//   across six prep kernels + launch gaps. Bottom-up models say prep ~60-95
//   -> model has under-predicted 3 rounds running. Decisive fork test:
//   launch all six prep kernels x3 (all idempotent; bsort's intra-run slot
//   permutation only permutes within bucket runs -> multiset identical).
//     total = 589 + 2*S + 12*g   (S = sum of six prep durs, g = gap)
//   H_prep (S~240): total ~1030-1110 -> R12 splits/fixes bsort.
//   H_gaps (S~90):  total ~750-810  -> R12 fuses the prep chain.

#define DF   256   // D_FEAT == FILTERS == 256
#define RSH  7
#define RPB  128   // rows per bucket = 1<<RSH
#define CAP  4800  // LDS edge capacity per bucket (mean 4096, sd 64 -> 11 sigma)
#define CHUNK 8192 // edges per block in A1/A3

typedef __attribute__((ext_vector_type(8))) short short8;  // 8 x bf16
typedef __attribute__((ext_vector_type(4))) float f32x4;

__device__ __forceinline__ unsigned short f2bf(float f) {
    unsigned int u = __float_as_uint(f);
    unsigned int r = (u + 0x7fffu + ((u >> 16) & 1u)) >> 16;  // RNE
    return (unsigned short)r;
}
// v_cvt_pk_bf16_f32: D.lo = bf16(a) RNE, D.hi = bf16(b) RNE (gfx950)
__device__ __forceinline__ unsigned int pack2(float a, float b) {
    unsigned int r;
    asm("v_cvt_pk_bf16_f32 %0, %1, %2" : "=v"(r) : "v"(a), "v"(b));
    return r;
}
__device__ __forceinline__ float bflo(unsigned int u) { return __uint_as_float(u << 16); }
__device__ __forceinline__ float bfhi(unsigned int u) { return __uint_as_float(u & 0xffff0000u); }

// A1: per-block bucket histogram; layout bh1[bucket][block] so bscan reads coalesced.
__global__ __launch_bounds__(256) void bhist_kernel(const int* __restrict__ row,
                                                    int* __restrict__ bh1, int NB, int NBLK, int E) {
    __shared__ int hist[1024];
    int t = threadIdx.x;
    for (int i = t; i < NB; i += 256) hist[i] = 0;
    __syncthreads();
    int base = blockIdx.x * CHUNK;
    int end = base + CHUNK; if (end > E) end = E;
    for (int i = base + t; i < end; i += 256)
        atomicAdd(&hist[row[i] >> RSH], 1);
    __syncthreads();
    for (int i = t; i < NB; i += 256)
        bh1[(size_t)i * NBLK + blockIdx.x] = hist[i];
}

// A2: per bucket (blockIdx), exclusive scan over NBLK block counts (NBLK <= 512).
__global__ __launch_bounds__(256) void bscan_kernel(const int* __restrict__ bh1,
                                                    int* __restrict__ bh2,
                                                    int* __restrict__ buckettot, int NB, int NBLK) {
    __shared__ int ps[256];
    int b = blockIdx.x, t = threadIdx.x;
    int e0 = 2 * t, e1 = 2 * t + 1;
    int v0 = (e0 < NBLK) ? bh1[(size_t)b * NBLK + e0] : 0;
    int v1 = (e1 < NBLK) ? bh1[(size_t)b * NBLK + e1] : 0;
    int tsum = v0 + v1;
    ps[t] = tsum;
    __syncthreads();
    for (int off = 1; off < 256; off <<= 1) {
        int v = (t >= off) ? ps[t - off] : 0;
        __syncthreads();
        ps[t] += v;
        __syncthreads();
    }
    int pre = ps[t] - tsum;  // exclusive
    if (e0 < NBLK) bh2[(size_t)e0 * NB + b] = pre;
    if (e1 < NBLK) bh2[(size_t)e1 * NB + b] = pre + v0;
    if (t == 255) buckettot[b] = ps[255];
}

// A2b: single block, exclusive scan of buckettot[0..NB) -> bucket_base[0..NB]
__global__ __launch_bounds__(1024) void btot_kernel(const int* __restrict__ buckettot,
                                                    int* __restrict__ bucket_base, int NB) {
    __shared__ int ps[1024];
    int t = threadIdx.x;
    int v = (t < NB) ? buckettot[t] : 0;
    ps[t] = v;
    __syncthreads();
    for (int off = 1; off < 1024; off <<= 1) {
        int u = (t >= off) ? ps[t - off] : 0;
        __syncthreads();
        ps[t] += u;
        __syncthreads();
    }
    if (t < NB) bucket_base[t] = ps[t] - v;
    if (t == 1023) bucket_base[NB] = ps[1023];
}

// A3: bsort: counting-sort the block's CHUNK edges by bucket in LDS, then
// flush sequentially (run-contiguous global writes). LDS ~94 KB.
__global__ __launch_bounds__(512) void bsort_kernel(const int* __restrict__ row,
                                                    const int* __restrict__ col,
                                                    const float* __restrict__ vals,
                                                    const int* __restrict__ bh2,
                                                    const int* __restrict__ bucket_base,
                                                    int2* __restrict__ bedge, int NB, int E) {
    __shared__ int2 sedge[CHUNK];            // 64 KB sorted edges
    __shared__ unsigned short sbkt[CHUNK];   // 16 KB slot -> bucket
    __shared__ int lhist[1024];              // hist, then reused as fill ctr
    __shared__ int lscan[1024];              // exclusive scan of hist
    __shared__ int lbase[1024];              // global dest base per bucket
    __shared__ int ps[512];
    int t = threadIdx.x, blk = blockIdx.x;
    int base = blk * CHUNK;
    int end = base + CHUNK; if (end > E) end = E;
    int n = end - base;
    for (int i = t; i < NB; i += 512) {
        lhist[i] = 0;
        lbase[i] = bucket_base[i] + bh2[(size_t)blk * NB + i];
    }
    __syncthreads();
    for (int i = base + t; i < end; i += 512)
        atomicAdd(&lhist[row[i] >> RSH], 1);
    __syncthreads();
    int e0 = 2 * t, e1 = 2 * t + 1;
    int v0 = (e0 < NB) ? lhist[e0] : 0;
    int v1 = (e1 < NB) ? lhist[e1] : 0;
    int tsum = v0 + v1;
    ps[t] = tsum;
    __syncthreads();
    for (int off = 1; off < 512; off <<= 1) {
        int v = (t >= off) ? ps[t - off] : 0;
        __syncthreads();
        ps[t] += v;
        __syncthreads();
    }
    int pre = ps[t] - tsum;
    if (e0 < NB) lscan[e0] = pre;
    if (e1 < NB) lscan[e1] = pre + v0;
    __syncthreads();
    for (int i = t; i < NB; i += 512) lhist[i] = 0;
    __syncthreads();
    for (int i = base + t; i < end; i += 512) {
        int r = row[i];
        int b = r >> RSH;
        int p = atomicAdd(&lhist[b], 1);
        int slot = lscan[b] + p;
        sedge[slot] = make_int2(((r & (RPB - 1)) << 17) | col[i], __float_as_int(vals[i]));
        sbkt[slot] = (unsigned short)b;
    }
    __syncthreads();
    for (int i = t; i < n; i += 512) {
        int b = sbkt[i];
        bedge[lbase[b] + (i - lscan[b])] = sedge[i];
    }
}

// Deg: block per bucket; LDS float accumulators; fused dinv. (R5-proven)
__global__ __launch_bounds__(256) void deg_kernel(const int2* __restrict__ bedge,
                                                  const int* __restrict__ bucket_base,
                                                  float* __restrict__ dinv, int N) {
    __shared__ float acc[RPB];
    int b = blockIdx.x, t = threadIdx.x;
    if (t < RPB) acc[t] = 0.f;
    __syncthreads();
    int s = bucket_base[b], e = bucket_base[b + 1];
    for (int i = s + t; i < e; i += 256) {
        int2 ed = bedge[i];
        atomicAdd(&acc[ed.x >> 17], __int_as_float(ed.y));
    }
    __syncthreads();
    if (t < RPB) {
        int r = b * RPB + t;
        if (r < N) {
            float d = acc[t];
            dinv[r] = (d > 0.f) ? (1.0f / sqrtf(d)) : 0.f;
        }
    }
}

// w[256][256] fp32 -> wbT[256][256] bf16 (one-time; RNE identical to pack2)
__global__ __launch_bounds__(256) void transpose_kernel(const float* __restrict__ w,
                                                        unsigned short* __restrict__ wbT) {
    __shared__ float tile[32][33];
    int bx = blockIdx.x * 32, by = blockIdx.y * 32;
    int tx = threadIdx.x, ty = threadIdx.y;  // dim(32,8)
    for (int j = ty; j < 32; j += 8) tile[j][tx] = w[(by + j) * DF + bx + tx];
    __syncthreads();
    for (int j = ty; j < 32; j += 8) wbT[(bx + j) * DF + by + tx] = f2bf(tile[tx][j]);
}

// MFMA bf16 GEMM v2: ZERO LDS / ZERO barriers (R10; ~= v1 in time).
__global__ __launch_bounds__(256, 2) void gemm_kernel(const float* __restrict__ x,
                                                      const unsigned short* __restrict__ wbT,
                                                      const float* __restrict__ dinv,
                                                      unsigned short* __restrict__ h, int N) {
    int tid = threadIdx.x;
    int by = blockIdx.x;
    int wv = tid >> 6, lane = tid & 63;
    int wr = wv >> 1, wc = wv & 1;
    int q = lane >> 4, mi = lane & 15;

    f32x4 acc[4][8];
#pragma unroll
    for (int i = 0; i < 4; ++i)
#pragma unroll
        for (int j = 0; j < 8; ++j) acc[i][j] = (f32x4){0.f, 0.f, 0.f, 0.f};

    const float* axp[4];
#pragma unroll
    for (int i = 0; i < 4; ++i) {
        int r = by * 128 + wr * 64 + i * 16 + mi;
        if (r >= N) r = N - 1;
        axp[i] = x + (long)r * DF + q * 8;
    }
    const unsigned short* bwp[8];
#pragma unroll
    for (int j = 0; j < 8; ++j)
        bwp[j] = wbT + (long)(wc * 128 + j * 16 + mi) * DF + q * 8;

    short8 af[4];
    {
        float4 p0[4], p1[4];
#pragma unroll
        for (int i = 0; i < 4; ++i) {
            p0[i] = *(const float4*)(axp[i]);
            p1[i] = *(const float4*)(axp[i] + 4);
        }
#pragma unroll
        for (int i = 0; i < 4; ++i) {
            uint4 pk;
            pk.x = pack2(p0[i].x, p0[i].y); pk.y = pack2(p0[i].z, p0[i].w);
            pk.z = pack2(p1[i].x, p1[i].y); pk.w = pack2(p1[i].z, p1[i].w);
            af[i] = *(short8*)&pk;
        }
    }

    for (int t = 0; t < 8; ++t) {
        int kk = t * 32;
        uint4 bw[8];
#pragma unroll
        for (int j = 0; j < 8; ++j)
            bw[j] = *(const uint4*)(bwp[j] + kk);
        float4 n0[4], n1[4];
        if (t < 7) {
#pragma unroll
            for (int i = 0; i < 4; ++i) {
                n0[i] = *(const float4*)(axp[i] + kk + 32);
                n1[i] = *(const float4*)(axp[i] + kk + 36);
            }
        }
#pragma unroll
        for (int j = 0; j < 8; ++j) {
            short8 bfj = *(short8*)&bw[j];
#pragma unroll
            for (int i = 0; i < 4; ++i)
                acc[i][j] = __builtin_amdgcn_mfma_f32_16x16x32_bf16(af[i], bfj, acc[i][j], 0, 0, 0);
        }
        if (t < 7) {
#pragma unroll
            for (int i = 0; i < 4; ++i) {
                uint4 pk;
                pk.x = pack2(n0[i].x, n0[i].y); pk.y = pack2(n0[i].z, n0[i].w);
                pk.z = pack2(n1[i].x, n1[i].y); pk.w = pack2(n1[i].z, n1[i].w);
                af[i] = *(short8*)&pk;
            }
        }
    }

    // C/D layout: col = lane&15, row = (lane>>4)*4 + reg   [verified m89/m91]
#pragma unroll
    for (int i = 0; i < 4; ++i) {
        int base_row = by * 128 + wr * 64 + i * 16 + q * 4;
#pragma unroll
        for (int r = 0; r < 4; ++r) {
            int rg = base_row + r;
            if (rg < N) {
                float dv = dinv[rg];
#pragma unroll
                for (int j = 0; j < 8; ++j) {
                    int cg = wc * 128 + j * 16 + mi;
                    h[(long)rg * DF + cg] = f2bf(dv * acc[i][j][r]);
                }
            }
        }
    }
}

// aggB: block per bucket. Counting-sort bucket edges into LDS, then one wave
// per row: split-wave gather. (R5-proven; sort hidden under gather saturation.)
__global__ __launch_bounds__(256) void aggb_kernel(const unsigned short* __restrict__ h,
                                                   const int2* __restrict__ bedge,
                                                   const int* __restrict__ bucket_base,
                                                   const float* __restrict__ dinv,
                                                   const float* __restrict__ bias,
                                                   float* __restrict__ out, int N) {
    __shared__ int2 ledge[CAP];
    __shared__ int cnt[RPB];
    __shared__ int lrs[RPB + 1];
    __shared__ int lfill[RPB];
    int b = blockIdx.x, t = threadIdx.x;
    int s = bucket_base[b], e = bucket_base[b + 1];
    int tot = e - s;
    int cap_end = s + (tot < CAP ? tot : CAP);
    if (t < RPB) { cnt[t] = 0; lfill[t] = 0; }
    __syncthreads();
    for (int i = s + t; i < cap_end; i += 256)
        atomicAdd(&cnt[bedge[i].x >> 17], 1);
    __syncthreads();
    int myc = 0;
    if (t < RPB) { myc = cnt[t]; lrs[t] = myc; }
    __syncthreads();
    for (int off = 1; off < RPB; off <<= 1) {
        int v = (t < RPB && t >= off) ? lrs[t - off] : 0;
        __syncthreads();
        if (t < RPB) lrs[t] += v;
        __syncthreads();
    }
    if (t < RPB) {
        int iv = lrs[t];
        lrs[t] = iv - myc;
        if (t == RPB - 1) lrs[RPB] = iv;
    }
    __syncthreads();
    for (int i = s + t; i < cap_end; i += 256) {
        int2 ed = bedge[i];
        int rl = ed.x >> 17;
        int p = lrs[rl] + atomicAdd(&lfill[rl], 1);
        ledge[p] = make_int2(ed.x & 0x1FFFF, ed.y);
    }
    __syncthreads();
    int wv = t >> 6, lane = t & 63;
    int half = lane >> 5;
    int fl = (lane & 31) * 8;
    const unsigned short* hp = h + fl;
    for (int lr = wv; lr < RPB; lr += 4) {
        int r = b * RPB + lr;
        if (r >= N) break;
        int rs = lrs[lr], re = lrs[lr + 1];
        float a0 = 0, a1 = 0, a2 = 0, a3 = 0, a4 = 0, a5 = 0, a6 = 0, a7 = 0;
        int i = rs + half;
        for (; i + 6 < re; i += 8) {
            int2 e0 = ledge[i], e1 = ledge[i + 2], e2 = ledge[i + 4], e3 = ledge[i + 6];
            uint4 u0 = *(const uint4*)(hp + (long)e0.x * DF);
            uint4 u1 = *(const uint4*)(hp + (long)e1.x * DF);
            uint4 u2 = *(const uint4*)(hp + (long)e2.x * DF);
            uint4 u3 = *(const uint4*)(hp + (long)e3.x * DF);
            float v0 = __int_as_float(e0.y), v1 = __int_as_float(e1.y);
            float v2 = __int_as_float(e2.y), v3 = __int_as_float(e3.y);
            a0 += v0 * bflo(u0.x) + v1 * bflo(u1.x) + v2 * bflo(u2.x) + v3 * bflo(u3.x);
            a1 += v0 * bfhi(u0.x) + v1 * bfhi(u1.x) + v2 * bfhi(u2.x) + v3 * bfhi(u3.x);
            a2 += v0 * bflo(u0.y) + v1 * bflo(u1.y) + v2 * bflo(u2.y) + v3 * bflo(u3.y);
            a3 += v0 * bfhi(u0.y) + v1 * bfhi(u1.y) + v2 * bfhi(u2.y) + v3 * bfhi(u3.y);
            a4 += v0 * bflo(u0.z) + v1 * bflo(u1.z) + v2 * bflo(u2.z) + v3 * bflo(u3.z);
            a5 += v0 * bfhi(u0.z) + v1 * bfhi(u1.z) + v2 * bfhi(u2.z) + v3 * bfhi(u3.z);
            a6 += v0 * bflo(u0.w) + v1 * bflo(u1.w) + v2 * bflo(u2.w) + v3 * bflo(u3.w);
            a7 += v0 * bfhi(u0.w) + v1 * bfhi(u1.w) + v2 * bfhi(u2.w) + v3 * bfhi(u3.w);
        }
        for (; i < re; i += 2) {
            int2 e0 = ledge[i];
            float v0 = __int_as_float(e0.y);
            uint4 u0 = *(const uint4*)(hp + (long)e0.x * DF);
            a0 += v0 * bflo(u0.x); a1 += v0 * bfhi(u0.x);
            a2 += v0 * bflo(u0.y); a3 += v0 * bfhi(u0.y);
            a4 += v0 * bflo(u0.z); a5 += v0 * bfhi(u0.z);
            a6 += v0 * bflo(u0.w); a7 += v0 * bfhi(u0.w);
        }
        for (int j = cap_end + half; j < e; j += 2) {
            int2 ed = bedge[j];
            if ((ed.x >> 17) == lr) {
                float v0 = __int_as_float(ed.y);
                uint4 u0 = *(const uint4*)(hp + (long)(ed.x & 0x1FFFF) * DF);
                a0 += v0 * bflo(u0.x); a1 += v0 * bfhi(u0.x);
                a2 += v0 * bflo(u0.y); a3 += v0 * bfhi(u0.y);
                a4 += v0 * bflo(u0.z); a5 += v0 * bfhi(u0.z);
                a6 += v0 * bflo(u0.w); a7 += v0 * bfhi(u0.w);
            }
        }
        a0 += __shfl_xor(a0, 32); a1 += __shfl_xor(a1, 32);
        a2 += __shfl_xor(a2, 32); a3 += __shfl_xor(a3, 32);
        a4 += __shfl_xor(a4, 32); a5 += __shfl_xor(a5, 32);
        a6 += __shfl_xor(a6, 32); a7 += __shfl_xor(a7, 32);
        if (half == 0) {
            float dr = dinv[r];
            float4 b0 = *(const float4*)(bias + fl);
            float4 b1 = *(const float4*)(bias + fl + 4);
            float4 o0, o1;
            o0.x = fmaxf(fmaf(dr, a0, b0.x), 0.f);
            o0.y = fmaxf(fmaf(dr, a1, b0.y), 0.f);
            o0.z = fmaxf(fmaf(dr, a2, b0.z), 0.f);
            o0.w = fmaxf(fmaf(dr, a3, b0.w), 0.f);
            o1.x = fmaxf(fmaf(dr, a4, b1.x), 0.f);
            o1.y = fmaxf(fmaf(dr, a5, b1.y), 0.f);
            o1.z = fmaxf(fmaf(dr, a6, b1.z), 0.f);
            o1.w = fmaxf(fmaf(dr, a7, b1.w), 0.f);
            *(float4*)(out + (long)r * DF + fl) = o0;
            *(float4*)(out + (long)r * DF + fl + 4) = o1;
        }
    }
}

extern "C" void kernel_launch(void* const* d_in, const int* in_sizes, int n_in,
                              void* d_out, int out_size, void* d_ws, size_t ws_size,
                              hipStream_t stream) {
    const float* x   = (const float*)d_in[0];
    const int* erow  = (const int*)d_in[1];
    const int* ecol  = (const int*)d_in[2];
    const float* ev  = (const float*)d_in[3];
    const float* w   = (const float*)d_in[4];
    const float* b   = (const float*)d_in[5];
    float* out = (float*)d_out;

    int N = in_sizes[0] / DF;
    int E = in_sizes[1];
    int NB = (N + RPB - 1) >> RSH;          // 782 (<=1024 supported)
    int NBLK = (E + CHUNK - 1) / CHUNK;     // 391 (<=512 supported)

    char* ws = (char*)d_ws;
    size_t Ea8 = (((size_t)E * 8) + 255) & ~(size_t)255;         // bedge
    size_t Hs  = (((size_t)N * DF * 2) + 255) & ~(size_t)255;    // h
    size_t Na  = (((size_t)N * 4) + 255) & ~(size_t)255;

    int2* bedge = (int2*)ws;
    char* reg2 = ws + Ea8;
    unsigned short* h = (unsigned short*)reg2;
    int* bh1 = (int*)reg2;                   // alias of h (A1..A3 only)
    int* bh2 = bh1 + (size_t)NB * NBLK;      // alias of h (A1..A3 only)
    char* reg3 = reg2 + Hs;
    unsigned short* wbT = (unsigned short*)reg3;   // 128 KB used of 256 KB slot
    float* dinv = (float*)(reg3 + 262144);
    int* buckettot = (int*)(reg3 + 262144 + Na);
    int* bucket_base = (int*)(reg3 + 262144 + Na + 8192);

    // MEASUREMENT: all six prep kernels x3 (idempotent). total = base + 2S + 12g.
    for (int rep = 0; rep < 3; ++rep)
        bhist_kernel<<<NBLK, 256, 0, stream>>>(erow, bh1, NB, NBLK, E);
    for (int rep = 0; rep < 3; ++rep)
        bscan_kernel<<<NB, 256, 0, stream>>>(bh1, bh2, buckettot, NB, NBLK);
    for (int rep = 0; rep < 3; ++rep)
        btot_kernel<<<1, 1024, 0, stream>>>(buckettot, bucket_base, NB);
    for (int rep = 0; rep < 3; ++rep)
        bsort_kernel<<<NBLK, 512, 0, stream>>>(erow, ecol, ev, bh2, bucket_base, bedge, NB, E);
    for (int rep = 0; rep < 3; ++rep)
        deg_kernel<<<NB, 256, 0, stream>>>(bedge, bucket_base, dinv, N);
    for (int rep = 0; rep < 3; ++rep)
        transpose_kernel<<<dim3(8, 8), dim3(32, 8), 0, stream>>>(w, wbT);
    gemm_kernel<<<dim3((N + 127) / 128), 256, 0, stream>>>(x, wbT, dinv, h, N);
    aggb_kernel<<<NB, 256, 0, stream>>>(h, bedge, bucket_base, dinv, b, out, N);
}

// Round 7
// 604.308 us; speedup vs baseline: 1.2305x; 1.2305x over previous
//
#include <hip/hip_runtime.h>
#include <hip/hip_bf16.h>

// GCN layer: out = relu( (D^-1/2 A D^-1/2) (x @ w) + b )
//
// R12 (from R11's solved ledger @ R10-base 589.2 us):
//   Ledger: aggb 250 + gemm 73 + prep 70 + gaps ~10 + FIXED HARNESS ~185
//   (8 reset/memset dispatches per iteration, dispatch-ID spacing 28 = 20
//   launches + 8; amplification-invariant -> untouchable).
//   Biggest controllable gap: gemm 73 vs ~25 roofline. Both R5 (LDS) and
//   R10 (zero-LDS) structures = 73 -> shared factor is 2 waves/SIMD
//   (launch_bounds(256,2)): ~200 cyc issue vs 900 cyc HBM A-latency with
//   1-deep prefetch. FIX (gemm v4): 64x256 tile, 4 waves of 32x128
//   (acc 64 VGPR), 2-deep A register pipeline, B in 4-wide groups,
//   launch_bounds(256,3) -> 3 waves/SIMD. Everything else unchanged;
//   prep back to single launches.

#define DF   256   // D_FEAT == FILTERS == 256
#define RSH  7
#define RPB  128   // rows per bucket = 1<<RSH
#define CAP  4800  // LDS edge capacity per bucket (mean 4096, sd 64 -> 11 sigma)
#define CHUNK 8192 // edges per block in A1/A3

typedef __attribute__((ext_vector_type(8))) short short8;  // 8 x bf16
typedef __attribute__((ext_vector_type(4))) float f32x4;

__device__ __forceinline__ unsigned short f2bf(float f) {
    unsigned int u = __float_as_uint(f);
    unsigned int r = (u + 0x7fffu + ((u >> 16) & 1u)) >> 16;  // RNE
    return (unsigned short)r;
}
// v_cvt_pk_bf16_f32: D.lo = bf16(a) RNE, D.hi = bf16(b) RNE (gfx950)
__device__ __forceinline__ unsigned int pack2(float a, float b) {
    unsigned int r;
    asm("v_cvt_pk_bf16_f32 %0, %1, %2" : "=v"(r) : "v"(a), "v"(b));
    return r;
}
__device__ __forceinline__ float bflo(unsigned int u) { return __uint_as_float(u << 16); }
__device__ __forceinline__ float bfhi(unsigned int u) { return __uint_as_float(u & 0xffff0000u); }

// A1: per-block bucket histogram; layout bh1[bucket][block] so bscan reads coalesced.
__global__ __launch_bounds__(256) void bhist_kernel(const int* __restrict__ row,
                                                    int* __restrict__ bh1, int NB, int NBLK, int E) {
    __shared__ int hist[1024];
    int t = threadIdx.x;
    for (int i = t; i < NB; i += 256) hist[i] = 0;
    __syncthreads();
    int base = blockIdx.x * CHUNK;
    int end = base + CHUNK; if (end > E) end = E;
    for (int i = base + t; i < end; i += 256)
        atomicAdd(&hist[row[i] >> RSH], 1);
    __syncthreads();
    for (int i = t; i < NB; i += 256)
        bh1[(size_t)i * NBLK + blockIdx.x] = hist[i];
}

// A2: per bucket (blockIdx), exclusive scan over NBLK block counts (NBLK <= 512).
__global__ __launch_bounds__(256) void bscan_kernel(const int* __restrict__ bh1,
                                                    int* __restrict__ bh2,
                                                    int* __restrict__ buckettot, int NB, int NBLK) {
    __shared__ int ps[256];
    int b = blockIdx.x, t = threadIdx.x;
    int e0 = 2 * t, e1 = 2 * t + 1;
    int v0 = (e0 < NBLK) ? bh1[(size_t)b * NBLK + e0] : 0;
    int v1 = (e1 < NBLK) ? bh1[(size_t)b * NBLK + e1] : 0;
    int tsum = v0 + v1;
    ps[t] = tsum;
    __syncthreads();
    for (int off = 1; off < 256; off <<= 1) {
        int v = (t >= off) ? ps[t - off] : 0;
        __syncthreads();
        ps[t] += v;
        __syncthreads();
    }
    int pre = ps[t] - tsum;  // exclusive
    if (e0 < NBLK) bh2[(size_t)e0 * NB + b] = pre;
    if (e1 < NBLK) bh2[(size_t)e1 * NB + b] = pre + v0;
    if (t == 255) buckettot[b] = ps[255];
}

// A2b: single block, exclusive scan of buckettot[0..NB) -> bucket_base[0..NB]
__global__ __launch_bounds__(1024) void btot_kernel(const int* __restrict__ buckettot,
                                                    int* __restrict__ bucket_base, int NB) {
    __shared__ int ps[1024];
    int t = threadIdx.x;
    int v = (t < NB) ? buckettot[t] : 0;
    ps[t] = v;
    __syncthreads();
    for (int off = 1; off < 1024; off <<= 1) {
        int u = (t >= off) ? ps[t - off] : 0;
        __syncthreads();
        ps[t] += u;
        __syncthreads();
    }
    if (t < NB) bucket_base[t] = ps[t] - v;
    if (t == 1023) bucket_base[NB] = ps[1023];
}

// A3: bsort: counting-sort the block's CHUNK edges by bucket in LDS, then
// flush sequentially (run-contiguous global writes). LDS ~94 KB.
__global__ __launch_bounds__(512) void bsort_kernel(const int* __restrict__ row,
                                                    const int* __restrict__ col,
                                                    const float* __restrict__ vals,
                                                    const int* __restrict__ bh2,
                                                    const int* __restrict__ bucket_base,
                                                    int2* __restrict__ bedge, int NB, int E) {
    __shared__ int2 sedge[CHUNK];            // 64 KB sorted edges
    __shared__ unsigned short sbkt[CHUNK];   // 16 KB slot -> bucket
    __shared__ int lhist[1024];              // hist, then reused as fill ctr
    __shared__ int lscan[1024];              // exclusive scan of hist
    __shared__ int lbase[1024];              // global dest base per bucket
    __shared__ int ps[512];
    int t = threadIdx.x, blk = blockIdx.x;
    int base = blk * CHUNK;
    int end = base + CHUNK; if (end > E) end = E;
    int n = end - base;
    for (int i = t; i < NB; i += 512) {
        lhist[i] = 0;
        lbase[i] = bucket_base[i] + bh2[(size_t)blk * NB + i];
    }
    __syncthreads();
    for (int i = base + t; i < end; i += 512)
        atomicAdd(&lhist[row[i] >> RSH], 1);
    __syncthreads();
    int e0 = 2 * t, e1 = 2 * t + 1;
    int v0 = (e0 < NB) ? lhist[e0] : 0;
    int v1 = (e1 < NB) ? lhist[e1] : 0;
    int tsum = v0 + v1;
    ps[t] = tsum;
    __syncthreads();
    for (int off = 1; off < 512; off <<= 1) {
        int v = (t >= off) ? ps[t - off] : 0;
        __syncthreads();
        ps[t] += v;
        __syncthreads();
    }
    int pre = ps[t] - tsum;
    if (e0 < NB) lscan[e0] = pre;
    if (e1 < NB) lscan[e1] = pre + v0;
    __syncthreads();
    for (int i = t; i < NB; i += 512) lhist[i] = 0;
    __syncthreads();
    for (int i = base + t; i < end; i += 512) {
        int r = row[i];
        int b = r >> RSH;
        int p = atomicAdd(&lhist[b], 1);
        int slot = lscan[b] + p;
        sedge[slot] = make_int2(((r & (RPB - 1)) << 17) | col[i], __float_as_int(vals[i]));
        sbkt[slot] = (unsigned short)b;
    }
    __syncthreads();
    for (int i = t; i < n; i += 512) {
        int b = sbkt[i];
        bedge[lbase[b] + (i - lscan[b])] = sedge[i];
    }
}

// Deg: block per bucket; LDS float accumulators; fused dinv. (R5-proven)
__global__ __launch_bounds__(256) void deg_kernel(const int2* __restrict__ bedge,
                                                  const int* __restrict__ bucket_base,
                                                  float* __restrict__ dinv, int N) {
    __shared__ float acc[RPB];
    int b = blockIdx.x, t = threadIdx.x;
    if (t < RPB) acc[t] = 0.f;
    __syncthreads();
    int s = bucket_base[b], e = bucket_base[b + 1];
    for (int i = s + t; i < e; i += 256) {
        int2 ed = bedge[i];
        atomicAdd(&acc[ed.x >> 17], __int_as_float(ed.y));
    }
    __syncthreads();
    if (t < RPB) {
        int r = b * RPB + t;
        if (r < N) {
            float d = acc[t];
            dinv[r] = (d > 0.f) ? (1.0f / sqrtf(d)) : 0.f;
        }
    }
}

// w[256][256] fp32 -> wbT[256][256] bf16 (one-time; RNE identical to pack2)
__global__ __launch_bounds__(256) void transpose_kernel(const float* __restrict__ w,
                                                        unsigned short* __restrict__ wbT) {
    __shared__ float tile[32][33];
    int bx = blockIdx.x * 32, by = blockIdx.y * 32;
    int tx = threadIdx.x, ty = threadIdx.y;  // dim(32,8)
    for (int j = ty; j < 32; j += 8) tile[j][tx] = w[(by + j) * DF + bx + tx];
    __syncthreads();
    for (int j = ty; j < 32; j += 8) wbT[(bx + j) * DF + by + tx] = f2bf(tile[tx][j]);
}

// MFMA bf16 GEMM v4: h'[r,:] = bf16( dinv[r] * (x[r,:] @ w) )
// Occupancy-focused: 64x256 tile, 4 waves of 32x128 (2x8 MFMA 16x16x32),
// acc = 64 VGPR. 2-deep A register pipeline (covers ~900cy HBM latency at
// 3 waves/SIMD); B from L2-resident wbT in 4-wide groups. Zero LDS.
__global__ __launch_bounds__(256, 3) void gemm_kernel(const float* __restrict__ x,
                                                      const unsigned short* __restrict__ wbT,
                                                      const float* __restrict__ dinv,
                                                      unsigned short* __restrict__ h, int N) {
    int tid = threadIdx.x;
    int by = blockIdx.x;
    int wv = tid >> 6, lane = tid & 63;
    int wrow = wv >> 1, wcol = wv & 1;
    int q = lane >> 4, mi = lane & 15;

    f32x4 acc[2][8];
#pragma unroll
    for (int i = 0; i < 2; ++i)
#pragma unroll
        for (int j = 0; j < 8; ++j) acc[i][j] = (f32x4){0.f, 0.f, 0.f, 0.f};

    const float* axp[2];
#pragma unroll
    for (int i = 0; i < 2; ++i) {
        int r = by * 64 + wrow * 32 + i * 16 + mi;
        if (r >= N) r = N - 1;
        axp[i] = x + (long)r * DF + q * 8;
    }
    const unsigned short* bwp = wbT + (long)(wcol * 128 + mi) * DF + q * 8;

    // 2-deep A pipeline: pa[s] holds K-step (t) with t&1==s
    float4 pa[2][4];
#pragma unroll
    for (int s = 0; s < 2; ++s) {
        pa[s][0] = *(const float4*)(axp[0] + s * 32);
        pa[s][1] = *(const float4*)(axp[0] + s * 32 + 4);
        pa[s][2] = *(const float4*)(axp[1] + s * 32);
        pa[s][3] = *(const float4*)(axp[1] + s * 32 + 4);
    }

#pragma unroll
    for (int t = 0; t < 8; ++t) {
        int kk = t * 32;
        int sl = t & 1;
        // consume slot sl -> bf16 frags
        short8 af[2];
        {
            uint4 pk;
            pk.x = pack2(pa[sl][0].x, pa[sl][0].y); pk.y = pack2(pa[sl][0].z, pa[sl][0].w);
            pk.z = pack2(pa[sl][1].x, pa[sl][1].y); pk.w = pack2(pa[sl][1].z, pa[sl][1].w);
            af[0] = *(short8*)&pk;
            pk.x = pack2(pa[sl][2].x, pa[sl][2].y); pk.y = pack2(pa[sl][2].z, pa[sl][2].w);
            pk.z = pack2(pa[sl][3].x, pa[sl][3].y); pk.w = pack2(pa[sl][3].z, pa[sl][3].w);
            af[1] = *(short8*)&pk;
        }
        // refill slot with K-step t+2 (HBM latency hides under 16 MFMAs + B loads)
        if (t < 6) {
            pa[sl][0] = *(const float4*)(axp[0] + kk + 64);
            pa[sl][1] = *(const float4*)(axp[0] + kk + 68);
            pa[sl][2] = *(const float4*)(axp[1] + kk + 64);
            pa[sl][3] = *(const float4*)(axp[1] + kk + 68);
        }
        // B in two 4-wide groups (keeps peak VGPR down; L2-latency overlap)
#pragma unroll
        for (int g = 0; g < 2; ++g) {
            uint4 bw[4];
#pragma unroll
            for (int j = 0; j < 4; ++j)
                bw[j] = *(const uint4*)(bwp + (long)(g * 4 + j) * 16 * DF + kk);
#pragma unroll
            for (int j = 0; j < 4; ++j) {
                short8 bfj = *(short8*)&bw[j];
                acc[0][g * 4 + j] = __builtin_amdgcn_mfma_f32_16x16x32_bf16(af[0], bfj, acc[0][g * 4 + j], 0, 0, 0);
                acc[1][g * 4 + j] = __builtin_amdgcn_mfma_f32_16x16x32_bf16(af[1], bfj, acc[1][g * 4 + j], 0, 0, 0);
            }
        }
    }

    // C/D layout: col = lane&15, row = (lane>>4)*4 + reg   [verified m89/m91]
#pragma unroll
    for (int i = 0; i < 2; ++i) {
        int base_row = by * 64 + wrow * 32 + i * 16 + q * 4;
#pragma unroll
        for (int r = 0; r < 4; ++r) {
            int rg = base_row + r;
            if (rg < N) {
                float dv = dinv[rg];
#pragma unroll
                for (int j = 0; j < 8; ++j) {
                    int cg = wcol * 128 + j * 16 + mi;
                    h[(long)rg * DF + cg] = f2bf(dv * acc[i][j][r]);
                }
            }
        }
    }
}

// aggB: block per bucket. Counting-sort bucket edges into LDS, then one wave
// per row: split-wave gather. (R5-proven; sort hidden under gather saturation.)
__global__ __launch_bounds__(256) void aggb_kernel(const unsigned short* __restrict__ h,
                                                   const int2* __restrict__ bedge,
                                                   const int* __restrict__ bucket_base,
                                                   const float* __restrict__ dinv,
                                                   const float* __restrict__ bias,
                                                   float* __restrict__ out, int N) {
    __shared__ int2 ledge[CAP];
    __shared__ int cnt[RPB];
    __shared__ int lrs[RPB + 1];
    __shared__ int lfill[RPB];
    int b = blockIdx.x, t = threadIdx.x;
    int s = bucket_base[b], e = bucket_base[b + 1];
    int tot = e - s;
    int cap_end = s + (tot < CAP ? tot : CAP);
    if (t < RPB) { cnt[t] = 0; lfill[t] = 0; }
    __syncthreads();
    for (int i = s + t; i < cap_end; i += 256)
        atomicAdd(&cnt[bedge[i].x >> 17], 1);
    __syncthreads();
    int myc = 0;
    if (t < RPB) { myc = cnt[t]; lrs[t] = myc; }
    __syncthreads();
    for (int off = 1; off < RPB; off <<= 1) {
        int v = (t < RPB && t >= off) ? lrs[t - off] : 0;
        __syncthreads();
        if (t < RPB) lrs[t] += v;
        __syncthreads();
    }
    if (t < RPB) {
        int iv = lrs[t];
        lrs[t] = iv - myc;
        if (t == RPB - 1) lrs[RPB] = iv;
    }
    __syncthreads();
    for (int i = s + t; i < cap_end; i += 256) {
        int2 ed = bedge[i];
        int rl = ed.x >> 17;
        int p = lrs[rl] + atomicAdd(&lfill[rl], 1);
        ledge[p] = make_int2(ed.x & 0x1FFFF, ed.y);
    }
    __syncthreads();
    int wv = t >> 6, lane = t & 63;
    int half = lane >> 5;
    int fl = (lane & 31) * 8;
    const unsigned short* hp = h + fl;
    for (int lr = wv; lr < RPB; lr += 4) {
        int r = b * RPB + lr;
        if (r >= N) break;
        int rs = lrs[lr], re = lrs[lr + 1];
        float a0 = 0, a1 = 0, a2 = 0, a3 = 0, a4 = 0, a5 = 0, a6 = 0, a7 = 0;
        int i = rs + half;
        for (; i + 6 < re; i += 8) {
            int2 e0 = ledge[i], e1 = ledge[i + 2], e2 = ledge[i + 4], e3 = ledge[i + 6];
            uint4 u0 = *(const uint4*)(hp + (long)e0.x * DF);
            uint4 u1 = *(const uint4*)(hp + (long)e1.x * DF);
            uint4 u2 = *(const uint4*)(hp + (long)e2.x * DF);
            uint4 u3 = *(const uint4*)(hp + (long)e3.x * DF);
            float v0 = __int_as_float(e0.y), v1 = __int_as_float(e1.y);
            float v2 = __int_as_float(e2.y), v3 = __int_as_float(e3.y);
            a0 += v0 * bflo(u0.x) + v1 * bflo(u1.x) + v2 * bflo(u2.x) + v3 * bflo(u3.x);
            a1 += v0 * bfhi(u0.x) + v1 * bfhi(u1.x) + v2 * bfhi(u2.x) + v3 * bfhi(u3.x);
            a2 += v0 * bflo(u0.y) + v1 * bflo(u1.y) + v2 * bflo(u2.y) + v3 * bflo(u3.y);
            a3 += v0 * bfhi(u0.y) + v1 * bfhi(u1.y) + v2 * bfhi(u2.y) + v3 * bfhi(u3.y);
            a4 += v0 * bflo(u0.z) + v1 * bflo(u1.z) + v2 * bflo(u2.z) + v3 * bflo(u3.z);
            a5 += v0 * bfhi(u0.z) + v1 * bfhi(u1.z) + v2 * bfhi(u2.z) + v3 * bfhi(u3.z);
            a6 += v0 * bflo(u0.w) + v1 * bflo(u1.w) + v2 * bflo(u2.w) + v3 * bflo(u3.w);
            a7 += v0 * bfhi(u0.w) + v1 * bfhi(u1.w) + v2 * bfhi(u2.w) + v3 * bfhi(u3.w);
        }
        for (; i < re; i += 2) {
            int2 e0 = ledge[i];
            float v0 = __int_as_float(e0.y);
            uint4 u0 = *(const uint4*)(hp + (long)e0.x * DF);
            a0 += v0 * bflo(u0.x); a1 += v0 * bfhi(u0.x);
            a2 += v0 * bflo(u0.y); a3 += v0 * bfhi(u0.y);
            a4 += v0 * bflo(u0.z); a5 += v0 * bfhi(u0.z);
            a6 += v0 * bflo(u0.w); a7 += v0 * bfhi(u0.w);
        }
        for (int j = cap_end + half; j < e; j += 2) {
            int2 ed = bedge[j];
            if ((ed.x >> 17) == lr) {
                float v0 = __int_as_float(ed.y);
                uint4 u0 = *(const uint4*)(hp + (long)(ed.x & 0x1FFFF) * DF);
                a0 += v0 * bflo(u0.x); a1 += v0 * bfhi(u0.x);
                a2 += v0 * bflo(u0.y); a3 += v0 * bfhi(u0.y);
                a4 += v0 * bflo(u0.z); a5 += v0 * bfhi(u0.z);
                a6 += v0 * bflo(u0.w); a7 += v0 * bfhi(u0.w);
            }
        }
        a0 += __shfl_xor(a0, 32); a1 += __shfl_xor(a1, 32);
        a2 += __shfl_xor(a2, 32); a3 += __shfl_xor(a3, 32);
        a4 += __shfl_xor(a4, 32); a5 += __shfl_xor(a5, 32);
        a6 += __shfl_xor(a6, 32); a7 += __shfl_xor(a7, 32);
        if (half == 0) {
            float dr = dinv[r];
            float4 b0 = *(const float4*)(bias + fl);
            float4 b1 = *(const float4*)(bias + fl + 4);
            float4 o0, o1;
            o0.x = fmaxf(fmaf(dr, a0, b0.x), 0.f);
            o0.y = fmaxf(fmaf(dr, a1, b0.y), 0.f);
            o0.z = fmaxf(fmaf(dr, a2, b0.z), 0.f);
            o0.w = fmaxf(fmaf(dr, a3, b0.w), 0.f);
            o1.x = fmaxf(fmaf(dr, a4, b1.x), 0.f);
            o1.y = fmaxf(fmaf(dr, a5, b1.y), 0.f);
            o1.z = fmaxf(fmaf(dr, a6, b1.z), 0.f);
            o1.w = fmaxf(fmaf(dr, a7, b1.w), 0.f);
            *(float4*)(out + (long)r * DF + fl) = o0;
            *(float4*)(out + (long)r * DF + fl + 4) = o1;
        }
    }
}

extern "C" void kernel_launch(void* const* d_in, const int* in_sizes, int n_in,
                              void* d_out, int out_size, void* d_ws, size_t ws_size,
                              hipStream_t stream) {
    const float* x   = (const float*)d_in[0];
    const int* erow  = (const int*)d_in[1];
    const int* ecol  = (const int*)d_in[2];
    const float* ev  = (const float*)d_in[3];
    const float* w   = (const float*)d_in[4];
    const float* b   = (const float*)d_in[5];
    float* out = (float*)d_out;

    int N = in_sizes[0] / DF;
    int E = in_sizes[1];
    int NB = (N + RPB - 1) >> RSH;          // 782 (<=1024 supported)
    int NBLK = (E + CHUNK - 1) / CHUNK;     // 391 (<=512 supported)

    char* ws = (char*)d_ws;
    size_t Ea8 = (((size_t)E * 8) + 255) & ~(size_t)255;         // bedge
    size_t Hs  = (((size_t)N * DF * 2) + 255) & ~(size_t)255;    // h
    size_t Na  = (((size_t)N * 4) + 255) & ~(size_t)255;

    int2* bedge = (int2*)ws;
    char* reg2 = ws + Ea8;
    unsigned short* h = (unsigned short*)reg2;
    int* bh1 = (int*)reg2;                   // alias of h (A1..A3 only)
    int* bh2 = bh1 + (size_t)NB * NBLK;      // alias of h (A1..A3 only)
    char* reg3 = reg2 + Hs;
    unsigned short* wbT = (unsigned short*)reg3;   // 128 KB used of 256 KB slot
    float* dinv = (float*)(reg3 + 262144);
    int* buckettot = (int*)(reg3 + 262144 + Na);
    int* bucket_base = (int*)(reg3 + 262144 + Na + 8192);

    bhist_kernel<<<NBLK, 256, 0, stream>>>(erow, bh1, NB, NBLK, E);
    bscan_kernel<<<NB, 256, 0, stream>>>(bh1, bh2, buckettot, NB, NBLK);
    btot_kernel<<<1, 1024, 0, stream>>>(buckettot, bucket_base, NB);
    bsort_kernel<<<NBLK, 512, 0, stream>>>(erow, ecol, ev, bh2, bucket_base, bedge, NB, E);
    deg_kernel<<<NB, 256, 0, stream>>>(bedge, bucket_base, dinv, N);
    transpose_kernel<<<dim3(8, 8), dim3(32, 8), 0, stream>>>(w, wbT);
    gemm_kernel<<<dim3((N + 63) / 64), 256, 0, stream>>>(x, wbT, dinv, h, N);
    aggb_kernel<<<NB, 256, 0, stream>>>(h, bedge, bucket_base, dinv, b, out, N);
}

// Round 8
// 591.621 us; speedup vs baseline: 1.2569x; 1.0214x over previous
//
#include <hip/hip_runtime.h>
#include <hip/hip_bf16.h>

// GCN layer: out = relu( (D^-1/2 A D^-1/2) (x @ w) + b )
//
// R13 (from R12's refuted-occupancy round; base = R10's 589.2 us):
//   Three different gemm main loops (R5 LDS, R10 zero-LDS, R12 occupancy)
//   all land at ~73+ us -> bottleneck is the SHARED epilogue: 26.2M 2-byte
//   h-stores = 1.6M scattered 32B write transactions @ ~23G/s (R1/R3
//   measured rate) ~= 70 us. Matches.
//   FIX: epilogue via per-wave LDS transpose: acc -> fp32 LDS [16][132]
//   (2-way bank = free; same-wave in-order LDS, no barrier), read back
//   row-contiguous, cvt_pk, store 16B dwordx4 (64B/lane contiguous).
//   Store instrs 409K -> 65K, granularity 2B -> 16B full lines.
//   Main loop/gemm grid identical to R10; everything else identical.

#define DF   256   // D_FEAT == FILTERS == 256
#define RSH  7
#define RPB  128   // rows per bucket = 1<<RSH
#define CAP  4800  // LDS edge capacity per bucket (mean 4096, sd 64 -> 11 sigma)
#define CHUNK 8192 // edges per block in A1/A3

typedef __attribute__((ext_vector_type(8))) short short8;  // 8 x bf16
typedef __attribute__((ext_vector_type(4))) float f32x4;

__device__ __forceinline__ unsigned short f2bf(float f) {
    unsigned int u = __float_as_uint(f);
    unsigned int r = (u + 0x7fffu + ((u >> 16) & 1u)) >> 16;  // RNE
    return (unsigned short)r;
}
// v_cvt_pk_bf16_f32: D.lo = bf16(a) RNE, D.hi = bf16(b) RNE (gfx950)
__device__ __forceinline__ unsigned int pack2(float a, float b) {
    unsigned int r;
    asm("v_cvt_pk_bf16_f32 %0, %1, %2" : "=v"(r) : "v"(a), "v"(b));
    return r;
}
__device__ __forceinline__ float bflo(unsigned int u) { return __uint_as_float(u << 16); }
__device__ __forceinline__ float bfhi(unsigned int u) { return __uint_as_float(u & 0xffff0000u); }

// A1: per-block bucket histogram; layout bh1[bucket][block] so bscan reads coalesced.
__global__ __launch_bounds__(256) void bhist_kernel(const int* __restrict__ row,
                                                    int* __restrict__ bh1, int NB, int NBLK, int E) {
    __shared__ int hist[1024];
    int t = threadIdx.x;
    for (int i = t; i < NB; i += 256) hist[i] = 0;
    __syncthreads();
    int base = blockIdx.x * CHUNK;
    int end = base + CHUNK; if (end > E) end = E;
    for (int i = base + t; i < end; i += 256)
        atomicAdd(&hist[row[i] >> RSH], 1);
    __syncthreads();
    for (int i = t; i < NB; i += 256)
        bh1[(size_t)i * NBLK + blockIdx.x] = hist[i];
}

// A2: per bucket (blockIdx), exclusive scan over NBLK block counts (NBLK <= 512).
__global__ __launch_bounds__(256) void bscan_kernel(const int* __restrict__ bh1,
                                                    int* __restrict__ bh2,
                                                    int* __restrict__ buckettot, int NB, int NBLK) {
    __shared__ int ps[256];
    int b = blockIdx.x, t = threadIdx.x;
    int e0 = 2 * t, e1 = 2 * t + 1;
    int v0 = (e0 < NBLK) ? bh1[(size_t)b * NBLK + e0] : 0;
    int v1 = (e1 < NBLK) ? bh1[(size_t)b * NBLK + e1] : 0;
    int tsum = v0 + v1;
    ps[t] = tsum;
    __syncthreads();
    for (int off = 1; off < 256; off <<= 1) {
        int v = (t >= off) ? ps[t - off] : 0;
        __syncthreads();
        ps[t] += v;
        __syncthreads();
    }
    int pre = ps[t] - tsum;  // exclusive
    if (e0 < NBLK) bh2[(size_t)e0 * NB + b] = pre;
    if (e1 < NBLK) bh2[(size_t)e1 * NB + b] = pre + v0;
    if (t == 255) buckettot[b] = ps[255];
}

// A2b: single block, exclusive scan of buckettot[0..NB) -> bucket_base[0..NB]
__global__ __launch_bounds__(1024) void btot_kernel(const int* __restrict__ buckettot,
                                                    int* __restrict__ bucket_base, int NB) {
    __shared__ int ps[1024];
    int t = threadIdx.x;
    int v = (t < NB) ? buckettot[t] : 0;
    ps[t] = v;
    __syncthreads();
    for (int off = 1; off < 1024; off <<= 1) {
        int u = (t >= off) ? ps[t - off] : 0;
        __syncthreads();
        ps[t] += u;
        __syncthreads();
    }
    if (t < NB) bucket_base[t] = ps[t] - v;
    if (t == 1023) bucket_base[NB] = ps[1023];
}

// A3: bsort: counting-sort the block's CHUNK edges by bucket in LDS, then
// flush sequentially (run-contiguous global writes). LDS ~94 KB.
__global__ __launch_bounds__(512) void bsort_kernel(const int* __restrict__ row,
                                                    const int* __restrict__ col,
                                                    const float* __restrict__ vals,
                                                    const int* __restrict__ bh2,
                                                    const int* __restrict__ bucket_base,
                                                    int2* __restrict__ bedge, int NB, int E) {
    __shared__ int2 sedge[CHUNK];            // 64 KB sorted edges
    __shared__ unsigned short sbkt[CHUNK];   // 16 KB slot -> bucket
    __shared__ int lhist[1024];              // hist, then reused as fill ctr
    __shared__ int lscan[1024];              // exclusive scan of hist
    __shared__ int lbase[1024];              // global dest base per bucket
    __shared__ int ps[512];
    int t = threadIdx.x, blk = blockIdx.x;
    int base = blk * CHUNK;
    int end = base + CHUNK; if (end > E) end = E;
    int n = end - base;
    for (int i = t; i < NB; i += 512) {
        lhist[i] = 0;
        lbase[i] = bucket_base[i] + bh2[(size_t)blk * NB + i];
    }
    __syncthreads();
    for (int i = base + t; i < end; i += 512)
        atomicAdd(&lhist[row[i] >> RSH], 1);
    __syncthreads();
    int e0 = 2 * t, e1 = 2 * t + 1;
    int v0 = (e0 < NB) ? lhist[e0] : 0;
    int v1 = (e1 < NB) ? lhist[e1] : 0;
    int tsum = v0 + v1;
    ps[t] = tsum;
    __syncthreads();
    for (int off = 1; off < 512; off <<= 1) {
        int v = (t >= off) ? ps[t - off] : 0;
        __syncthreads();
        ps[t] += v;
        __syncthreads();
    }
    int pre = ps[t] - tsum;
    if (e0 < NB) lscan[e0] = pre;
    if (e1 < NB) lscan[e1] = pre + v0;
    __syncthreads();
    for (int i = t; i < NB; i += 512) lhist[i] = 0;
    __syncthreads();
    for (int i = base + t; i < end; i += 512) {
        int r = row[i];
        int b = r >> RSH;
        int p = atomicAdd(&lhist[b], 1);
        int slot = lscan[b] + p;
        sedge[slot] = make_int2(((r & (RPB - 1)) << 17) | col[i], __float_as_int(vals[i]));
        sbkt[slot] = (unsigned short)b;
    }
    __syncthreads();
    for (int i = t; i < n; i += 512) {
        int b = sbkt[i];
        bedge[lbase[b] + (i - lscan[b])] = sedge[i];
    }
}

// Deg: block per bucket; LDS float accumulators; fused dinv. (R5-proven)
__global__ __launch_bounds__(256) void deg_kernel(const int2* __restrict__ bedge,
                                                  const int* __restrict__ bucket_base,
                                                  float* __restrict__ dinv, int N) {
    __shared__ float acc[RPB];
    int b = blockIdx.x, t = threadIdx.x;
    if (t < RPB) acc[t] = 0.f;
    __syncthreads();
    int s = bucket_base[b], e = bucket_base[b + 1];
    for (int i = s + t; i < e; i += 256) {
        int2 ed = bedge[i];
        atomicAdd(&acc[ed.x >> 17], __int_as_float(ed.y));
    }
    __syncthreads();
    if (t < RPB) {
        int r = b * RPB + t;
        if (r < N) {
            float d = acc[t];
            dinv[r] = (d > 0.f) ? (1.0f / sqrtf(d)) : 0.f;
        }
    }
}

// w[256][256] fp32 -> wbT[256][256] bf16 (one-time; RNE identical to pack2)
__global__ __launch_bounds__(256) void transpose_kernel(const float* __restrict__ w,
                                                        unsigned short* __restrict__ wbT) {
    __shared__ float tile[32][33];
    int bx = blockIdx.x * 32, by = blockIdx.y * 32;
    int tx = threadIdx.x, ty = threadIdx.y;  // dim(32,8)
    for (int j = ty; j < 32; j += 8) tile[j][tx] = w[(by + j) * DF + bx + tx];
    __syncthreads();
    for (int j = ty; j < 32; j += 8) wbT[(bx + j) * DF + by + tx] = f2bf(tile[tx][j]);
}

// MFMA bf16 GEMM v5: R10 main loop (zero-LDS, 128x256, 1-deep A prefetch)
// + NEW epilogue: per-wave LDS transpose -> coalesced 16B h stores.
__global__ __launch_bounds__(256, 2) void gemm_kernel(const float* __restrict__ x,
                                                      const unsigned short* __restrict__ wbT,
                                                      const float* __restrict__ dinv,
                                                      unsigned short* __restrict__ h, int N) {
    __shared__ float tl[4][16][132];   // per-wave transpose tile (33 KB)
    int tid = threadIdx.x;
    int by = blockIdx.x;
    int wv = tid >> 6, lane = tid & 63;
    int wr = wv >> 1, wc = wv & 1;
    int q = lane >> 4, mi = lane & 15;

    f32x4 acc[4][8];
#pragma unroll
    for (int i = 0; i < 4; ++i)
#pragma unroll
        for (int j = 0; j < 8; ++j) acc[i][j] = (f32x4){0.f, 0.f, 0.f, 0.f};

    const float* axp[4];
#pragma unroll
    for (int i = 0; i < 4; ++i) {
        int r = by * 128 + wr * 64 + i * 16 + mi;
        if (r >= N) r = N - 1;
        axp[i] = x + (long)r * DF + q * 8;
    }
    const unsigned short* bwp[8];
#pragma unroll
    for (int j = 0; j < 8; ++j)
        bwp[j] = wbT + (long)(wc * 128 + j * 16 + mi) * DF + q * 8;

    short8 af[4];
    {
        float4 p0[4], p1[4];
#pragma unroll
        for (int i = 0; i < 4; ++i) {
            p0[i] = *(const float4*)(axp[i]);
            p1[i] = *(const float4*)(axp[i] + 4);
        }
#pragma unroll
        for (int i = 0; i < 4; ++i) {
            uint4 pk;
            pk.x = pack2(p0[i].x, p0[i].y); pk.y = pack2(p0[i].z, p0[i].w);
            pk.z = pack2(p1[i].x, p1[i].y); pk.w = pack2(p1[i].z, p1[i].w);
            af[i] = *(short8*)&pk;
        }
    }

    for (int t = 0; t < 8; ++t) {
        int kk = t * 32;
        uint4 bw[8];
#pragma unroll
        for (int j = 0; j < 8; ++j)
            bw[j] = *(const uint4*)(bwp[j] + kk);
        float4 n0[4], n1[4];
        if (t < 7) {
#pragma unroll
            for (int i = 0; i < 4; ++i) {
                n0[i] = *(const float4*)(axp[i] + kk + 32);
                n1[i] = *(const float4*)(axp[i] + kk + 36);
            }
        }
#pragma unroll
        for (int j = 0; j < 8; ++j) {
            short8 bfj = *(short8*)&bw[j];
#pragma unroll
            for (int i = 0; i < 4; ++i)
                acc[i][j] = __builtin_amdgcn_mfma_f32_16x16x32_bf16(af[i], bfj, acc[i][j], 0, 0, 0);
        }
        if (t < 7) {
#pragma unroll
            for (int i = 0; i < 4; ++i) {
                uint4 pk;
                pk.x = pack2(n0[i].x, n0[i].y); pk.y = pack2(n0[i].z, n0[i].w);
                pk.z = pack2(n1[i].x, n1[i].y); pk.w = pack2(n1[i].z, n1[i].w);
                af[i] = *(short8*)&pk;
            }
        }
    }

    // Epilogue: C/D layout col=lane&15, row=(lane>>4)*4+reg [m89/m91].
    // Per-wave LDS transpose (in-order same-wave LDS; no block barrier),
    // then row-contiguous 16B stores (64B/lane).
    int row16 = lane & 15;   // output row within 16-row block
    int seg = lane >> 4;     // 32-col segment
#pragma unroll
    for (int i = 0; i < 4; ++i) {
        int base_row = by * 128 + wr * 64 + i * 16;
        float dv[4];
#pragma unroll
        for (int r = 0; r < 4; ++r) {
            int rg = base_row + q * 4 + r;
            dv[r] = dinv[rg < N ? rg : (N - 1)];
        }
#pragma unroll
        for (int j = 0; j < 8; ++j)
#pragma unroll
            for (int r = 0; r < 4; ++r)
                tl[wv][q * 4 + r][j * 16 + mi] = dv[r] * acc[i][j][r];
        asm volatile("s_waitcnt lgkmcnt(0)" ::: "memory");
        int rg2 = base_row + row16;
        if (rg2 < N) {
            const float* lp = &tl[wv][row16][seg * 32];
            unsigned short* hp2 = h + (long)rg2 * DF + wc * 128 + seg * 32;
#pragma unroll
            for (int k = 0; k < 4; ++k) {
                float4 u0 = *(const float4*)(lp + k * 8);
                float4 u1 = *(const float4*)(lp + k * 8 + 4);
                uint4 pk;
                pk.x = pack2(u0.x, u0.y); pk.y = pack2(u0.z, u0.w);
                pk.z = pack2(u1.x, u1.y); pk.w = pack2(u1.z, u1.w);
                *(uint4*)(hp2 + k * 8) = pk;
            }
        }
        // next i's LDS writes cannot pass this i's reads (per-wave in-order LDS)
    }
}

// aggB: block per bucket. Counting-sort bucket edges into LDS, then one wave
// per row: split-wave gather. (R5-proven; sort hidden under gather saturation.)
__global__ __launch_bounds__(256) void aggb_kernel(const unsigned short* __restrict__ h,
                                                   const int2* __restrict__ bedge,
                                                   const int* __restrict__ bucket_base,
                                                   const float* __restrict__ dinv,
                                                   const float* __restrict__ bias,
                                                   float* __restrict__ out, int N) {
    __shared__ int2 ledge[CAP];
    __shared__ int cnt[RPB];
    __shared__ int lrs[RPB + 1];
    __shared__ int lfill[RPB];
    int b = blockIdx.x, t = threadIdx.x;
    int s = bucket_base[b], e = bucket_base[b + 1];
    int tot = e - s;
    int cap_end = s + (tot < CAP ? tot : CAP);
    if (t < RPB) { cnt[t] = 0; lfill[t] = 0; }
    __syncthreads();
    for (int i = s + t; i < cap_end; i += 256)
        atomicAdd(&cnt[bedge[i].x >> 17], 1);
    __syncthreads();
    int myc = 0;
    if (t < RPB) { myc = cnt[t]; lrs[t] = myc; }
    __syncthreads();
    for (int off = 1; off < RPB; off <<= 1) {
        int v = (t < RPB && t >= off) ? lrs[t - off] : 0;
        __syncthreads();
        if (t < RPB) lrs[t] += v;
        __syncthreads();
    }
    if (t < RPB) {
        int iv = lrs[t];
        lrs[t] = iv - myc;
        if (t == RPB - 1) lrs[RPB] = iv;
    }
    __syncthreads();
    for (int i = s + t; i < cap_end; i += 256) {
        int2 ed = bedge[i];
        int rl = ed.x >> 17;
        int p = lrs[rl] + atomicAdd(&lfill[rl], 1);
        ledge[p] = make_int2(ed.x & 0x1FFFF, ed.y);
    }
    __syncthreads();
    int wv = t >> 6, lane = t & 63;
    int half = lane >> 5;
    int fl = (lane & 31) * 8;
    const unsigned short* hp = h + fl;
    for (int lr = wv; lr < RPB; lr += 4) {
        int r = b * RPB + lr;
        if (r >= N) break;
        int rs = lrs[lr], re = lrs[lr + 1];
        float a0 = 0, a1 = 0, a2 = 0, a3 = 0, a4 = 0, a5 = 0, a6 = 0, a7 = 0;
        int i = rs + half;
        for (; i + 6 < re; i += 8) {
            int2 e0 = ledge[i], e1 = ledge[i + 2], e2 = ledge[i + 4], e3 = ledge[i + 6];
            uint4 u0 = *(const uint4*)(hp + (long)e0.x * DF);
            uint4 u1 = *(const uint4*)(hp + (long)e1.x * DF);
            uint4 u2 = *(const uint4*)(hp + (long)e2.x * DF);
            uint4 u3 = *(const uint4*)(hp + (long)e3.x * DF);
            float v0 = __int_as_float(e0.y), v1 = __int_as_float(e1.y);
            float v2 = __int_as_float(e2.y), v3 = __int_as_float(e3.y);
            a0 += v0 * bflo(u0.x) + v1 * bflo(u1.x) + v2 * bflo(u2.x) + v3 * bflo(u3.x);
            a1 += v0 * bfhi(u0.x) + v1 * bfhi(u1.x) + v2 * bfhi(u2.x) + v3 * bfhi(u3.x);
            a2 += v0 * bflo(u0.y) + v1 * bflo(u1.y) + v2 * bflo(u2.y) + v3 * bflo(u3.y);
            a3 += v0 * bfhi(u0.y) + v1 * bfhi(u1.y) + v2 * bfhi(u2.y) + v3 * bfhi(u3.y);
            a4 += v0 * bflo(u0.z) + v1 * bflo(u1.z) + v2 * bflo(u2.z) + v3 * bflo(u3.z);
            a5 += v0 * bfhi(u0.z) + v1 * bfhi(u1.z) + v2 * bfhi(u2.z) + v3 * bfhi(u3.z);
            a6 += v0 * bflo(u0.w) + v1 * bflo(u1.w) + v2 * bflo(u2.w) + v3 * bflo(u3.w);
            a7 += v0 * bfhi(u0.w) + v1 * bfhi(u1.w) + v2 * bfhi(u2.w) + v3 * bfhi(u3.w);
        }
        for (; i < re; i += 2) {
            int2 e0 = ledge[i];
            float v0 = __int_as_float(e0.y);
            uint4 u0 = *(const uint4*)(hp + (long)e0.x * DF);
            a0 += v0 * bflo(u0.x); a1 += v0 * bfhi(u0.x);
            a2 += v0 * bflo(u0.y); a3 += v0 * bfhi(u0.y);
            a4 += v0 * bflo(u0.z); a5 += v0 * bfhi(u0.z);
            a6 += v0 * bflo(u0.w); a7 += v0 * bfhi(u0.w);
        }
        for (int j = cap_end + half; j < e; j += 2) {
            int2 ed = bedge[j];
            if ((ed.x >> 17) == lr) {
                float v0 = __int_as_float(ed.y);
                uint4 u0 = *(const uint4*)(hp + (long)(ed.x & 0x1FFFF) * DF);
                a0 += v0 * bflo(u0.x); a1 += v0 * bfhi(u0.x);
                a2 += v0 * bflo(u0.y); a3 += v0 * bfhi(u0.y);
                a4 += v0 * bflo(u0.z); a5 += v0 * bfhi(u0.z);
                a6 += v0 * bflo(u0.w); a7 += v0 * bfhi(u0.w);
            }
        }
        a0 += __shfl_xor(a0, 32); a1 += __shfl_xor(a1, 32);
        a2 += __shfl_xor(a2, 32); a3 += __shfl_xor(a3, 32);
        a4 += __shfl_xor(a4, 32); a5 += __shfl_xor(a5, 32);
        a6 += __shfl_xor(a6, 32); a7 += __shfl_xor(a7, 32);
        if (half == 0) {
            float dr = dinv[r];
            float4 b0 = *(const float4*)(bias + fl);
            float4 b1 = *(const float4*)(bias + fl + 4);
            float4 o0, o1;
            o0.x = fmaxf(fmaf(dr, a0, b0.x), 0.f);
            o0.y = fmaxf(fmaf(dr, a1, b0.y), 0.f);
            o0.z = fmaxf(fmaf(dr, a2, b0.z), 0.f);
            o0.w = fmaxf(fmaf(dr, a3, b0.w), 0.f);
            o1.x = fmaxf(fmaf(dr, a4, b1.x), 0.f);
            o1.y = fmaxf(fmaf(dr, a5, b1.y), 0.f);
            o1.z = fmaxf(fmaf(dr, a6, b1.z), 0.f);
            o1.w = fmaxf(fmaf(dr, a7, b1.w), 0.f);
            *(float4*)(out + (long)r * DF + fl) = o0;
            *(float4*)(out + (long)r * DF + fl + 4) = o1;
        }
    }
}

extern "C" void kernel_launch(void* const* d_in, const int* in_sizes, int n_in,
                              void* d_out, int out_size, void* d_ws, size_t ws_size,
                              hipStream_t stream) {
    const float* x   = (const float*)d_in[0];
    const int* erow  = (const int*)d_in[1];
    const int* ecol  = (const int*)d_in[2];
    const float* ev  = (const float*)d_in[3];
    const float* w   = (const float*)d_in[4];
    const float* b   = (const float*)d_in[5];
    float* out = (float*)d_out;

    int N = in_sizes[0] / DF;
    int E = in_sizes[1];
    int NB = (N + RPB - 1) >> RSH;          // 782 (<=1024 supported)
    int NBLK = (E + CHUNK - 1) / CHUNK;     // 391 (<=512 supported)

    char* ws = (char*)d_ws;
    size_t Ea8 = (((size_t)E * 8) + 255) & ~(size_t)255;         // bedge
    size_t Hs  = (((size_t)N * DF * 2) + 255) & ~(size_t)255;    // h
    size_t Na  = (((size_t)N * 4) + 255) & ~(size_t)255;

    int2* bedge = (int2*)ws;
    char* reg2 = ws + Ea8;
    unsigned short* h = (unsigned short*)reg2;
    int* bh1 = (int*)reg2;                   // alias of h (A1..A3 only)
    int* bh2 = bh1 + (size_t)NB * NBLK;      // alias of h (A1..A3 only)
    char* reg3 = reg2 + Hs;
    unsigned short* wbT = (unsigned short*)reg3;   // 128 KB used of 256 KB slot
    float* dinv = (float*)(reg3 + 262144);
    int* buckettot = (int*)(reg3 + 262144 + Na);
    int* bucket_base = (int*)(reg3 + 262144 + Na + 8192);

    bhist_kernel<<<NBLK, 256, 0, stream>>>(erow, bh1, NB, NBLK, E);
    bscan_kernel<<<NB, 256, 0, stream>>>(bh1, bh2, buckettot, NB, NBLK);
    btot_kernel<<<1, 1024, 0, stream>>>(buckettot, bucket_base, NB);
    bsort_kernel<<<NBLK, 512, 0, stream>>>(erow, ecol, ev, bh2, bucket_base, bedge, NB, E);
    deg_kernel<<<NB, 256, 0, stream>>>(bedge, bucket_base, dinv, N);
    transpose_kernel<<<dim3(8, 8), dim3(32, 8), 0, stream>>>(w, wbT);
    gemm_kernel<<<dim3((N + 127) / 128), 256, 0, stream>>>(x, wbT, dinv, h, N);
    aggb_kernel<<<NB, 256, 0, stream>>>(h, bedge, bucket_base, dinv, b, out, N);
}